// Round 14
// baseline (210.155 us; speedup 1.0000x reference)
//
#include <hip/hip_runtime.h>

#define QLEN 1024
#define KLEN 2048   // MLEN + QLEN

typedef float f32x4 __attribute__((ext_vector_type(4)));

static constexpr float INV2PI = 0.15915494309189535f;
static constexpr float TGUARD = 3e-5f;

// ---------------------------------------------------------------------------
// Fused projection + sincos precompute (verified rounds 2-13).
// Layout per token: float4 index = (tok*12 + part*4 + c)*32 + bh
//   part 0 = p, 1 = sin(R*p), 2 = cos(R*p);  c = d>>2;  elem = d&3
// ---------------------------------------------------------------------------
__global__ __launch_bounds__(256) void fa_proj_kernel(
    const float* __restrict__ h, const float* __restrict__ mems,
    const float* __restrict__ Wq, const float* __restrict__ Wk,
    const float* __restrict__ paramR,
    float* __restrict__ Rq3, float* __restrict__ Rk3)
{
    __shared__ float inT[128 * 36];
    const int tid  = threadIdx.x;
    const bool isQ = blockIdx.x < 128;
    const int  blk = isQ ? blockIdx.x : blockIdx.x - 128;
    const int row0 = blk * 32;
    const float* W   = isQ ? Wq : Wk;
    float*      out3 = isQ ? Rq3 : Rk3;

    for (int idx = tid; idx < 32 * 128; idx += 256) {
        int r = idx >> 7;
        int e = idx & 127;
        int grow = row0 + r;
        float v;
        if (isQ)               v = h[(size_t)grow * 128 + e];
        else if (grow < 4096)  v = mems[(size_t)grow * 128 + e];
        else                   v = h[(size_t)(grow - 4096) * 128 + e];
        inT[e * 36 + r] = v;
    }
    __syncthreads();

    const int col  = tid & 127;
    const int half = tid >> 7;

    float acc[16];
#pragma unroll
    for (int j = 0; j < 16; ++j) acc[j] = 0.0f;

#pragma unroll 2
    for (int e = 0; e < 128; ++e) {
        float w = W[e * 128 + col];
        const float4* ap = reinterpret_cast<const float4*>(&inT[e * 36 + half * 16]);
        float4 a0 = ap[0], a1 = ap[1], a2 = ap[2], a3 = ap[3];
        float av[16];
        av[0]=a0.x; av[1]=a0.y; av[2]=a0.z; av[3]=a0.w;
        av[4]=a1.x; av[5]=a1.y; av[6]=a1.z; av[7]=a1.w;
        av[8]=a2.x; av[9]=a2.y; av[10]=a2.z; av[11]=a2.w;
        av[12]=a3.x; av[13]=a3.y; av[14]=a3.z; av[15]=a3.w;
#pragma unroll
        for (int j = 0; j < 16; ++j) acc[j] = fmaf(av[j], w, acc[j]);
    }

    const int hh = col >> 4;
    const int d  = col & 15;
    const float Rrev = paramR[hh] * INV2PI;

#pragma unroll
    for (int j = 0; j < 16; ++j) {
        int r   = row0 + half * 16 + j;
        int tok = r >> 2;
        int b   = r & 3;
        int bh  = b * 8 + hh;
        float p = acc[j];
        float s = __builtin_amdgcn_sinf(Rrev * p);
        float c = __builtin_amdgcn_cosf(Rrev * p);
        int base = ((tok * 12 + (d >> 2)) * 32 + bh) * 4 + (d & 3);
        out3[base]        = p;
        out3[base + 512]  = s;
        out3[base + 1024] = c;
    }
}

// ---------------------------------------------------------------------------
// Main kernel — TQ=2 under launch_bounds(256,2).
// Diagnosis r13: VGPR=84 + zero scratch + pinned 96-float state = the
// allocator spills loop-invariant q-state to AGPRs; every use costs a
// v_accvgpr_read on the VALU pipe (~190 cyc/token) — the 2x instruction
// bloat seen since r6. Evidence r5: launch_bounds(256,2) is the one config
// where the allocator built a 128-reg arch file. So: shrink the working
// set to ~100 regs (TQ=2) AND give the (256,2) budget -> state genuinely
// resident, zero AGPR traffic.
//   Block = 4 waves; wave owns 2 q-rows (qb = x*8 + wv*2).
//   Lane (dhalf = l>>5, bh = l&31) handles 8 of 16 d's for both q's.
//   2-token LDS windows (24576 B, dbuf, global_load_lds).
//   Bare-asm counted barrier vmcnt(2) with sched_barrier(0) fences (r13).
//   Grid 2048 = 128 q-blocks x 16 k-chunks (bid&15, XCD-clean).
// ---------------------------------------------------------------------------
__global__ __launch_bounds__(256, 2) void fa_fourier_main(
    const float* __restrict__ Rq3, const float* __restrict__ Rk3,
    const float* __restrict__ paramR, float* __restrict__ out)
{
    __shared__ f32x4 kbuf[2][768];    // 2 x (2 tok x 12 x 32) float4 = 24576 B

    const int tid   = threadIdx.x;
    const int wv    = tid >> 6;
    const int l     = tid & 63;
    const int dhalf = l >> 5;          // which 8 of the 16 d's
    const int bh    = l & 31;
    const int bid   = blockIdx.x;
    const int ch    = bid & 15;        // k-chunk (128 tokens), XCD-pinned
    const int x     = bid >> 4;        // q-block 0..127
    const int k0    = ch * 128;
    const int qb    = x * 8 + wv * 2;

    const float R = paramR[bh & 7];

    // q-state: 2 q x {p,s,c} x 2 f32x4 (own 8 d's) = 48 floats, pinned.
    f32x4 qp[2][2], qs[2][2], qc[2][2];
    {
        const f32x4* qsrc = reinterpret_cast<const f32x4*>(Rq3);
#pragma unroll
        for (int q = 0; q < 2; ++q) {
            size_t tb = (size_t)(qb + q) * 12;
#pragma unroll
            for (int j = 0; j < 2; ++j) {
                qp[q][j] = qsrc[(tb + 0 + dhalf * 2 + j) * 32 + bh];
                qs[q][j] = qsrc[(tb + 4 + dhalf * 2 + j) * 32 + bh];
                qc[q][j] = qsrc[(tb + 8 + dhalf * 2 + j) * 32 + bh];
            }
        }
    }
    // Opaque pin: asm results cannot be rematerialized.
#pragma unroll
    for (int q = 0; q < 2; ++q)
#pragma unroll
        for (int j = 0; j < 2; ++j)
            asm volatile("" : "+v"(qp[q][j]), "+v"(qs[q][j]), "+v"(qc[q][j]));

    const f32x4* ksrc = reinterpret_cast<const f32x4*>(Rk3);

    // this lane stores q-row qb+dhalf
    float* outRow = out + ((size_t)(qb + dhalf) * KLEN + k0) * 32 + bh;

    // stage 2-token window w into buffer parity (3 x 16B per thread)
    auto stage = [&](int w, int parity) {
        size_t gbase = (size_t)(k0 + w * 2) * 384;
#pragma unroll
        for (int i = 0; i < 3; ++i) {
            int fi = i * 256 + tid;
            __builtin_amdgcn_global_load_lds(
                (const __attribute__((address_space(1))) void*)(ksrc + gbase + fi),
                (__attribute__((address_space(3))) void*)(&kbuf[parity][fi]),
                16, 0, 0);
        }
    };

    stage(0, 0);
    __builtin_amdgcn_sched_barrier(0);
    asm volatile("s_waitcnt vmcnt(0)\n\ts_barrier");
    __builtin_amdgcn_sched_barrier(0);

    for (int w = 0; w < 64; ++w) {
        if (w < 63) stage(w + 1, (w + 1) & 1);
        const f32x4* kb = kbuf[w & 1] + bh;

#pragma unroll
        for (int t = 0; t < 2; ++t) {
            // k half-state: 6 f32x4 (compile-time offsets)
            f32x4 kp0 = kb[(t * 12 + 0 + dhalf * 2 + 0) * 32];
            f32x4 kp1 = kb[(t * 12 + 0 + dhalf * 2 + 1) * 32];
            f32x4 ks0 = kb[(t * 12 + 4 + dhalf * 2 + 0) * 32];
            f32x4 ks1 = kb[(t * 12 + 4 + dhalf * 2 + 1) * 32];
            f32x4 kc0 = kb[(t * 12 + 8 + dhalf * 2 + 0) * 32];
            f32x4 kc1 = kb[(t * 12 + 8 + dhalf * 2 + 1) * 32];

            float g[2];
#pragma unroll
            for (int q = 0; q < 2; ++q) {
                float u0 = qp[q][0][0] - kp0[0];
                float u1 = qp[q][0][1] - kp0[1];
                float u2 = qp[q][0][2] - kp0[2];
                float u3 = qp[q][0][3] - kp0[3];
                float u4 = qp[q][1][0] - kp1[0];
                float u5 = qp[q][1][1] - kp1[1];
                float u6 = qp[q][1][2] - kp1[2];
                float u7 = qp[q][1][3] - kp1[3];
                float n0 = fmaf(qs[q][0][0], kc0[0], -(qc[q][0][0] * ks0[0]));
                float n1 = fmaf(qs[q][0][1], kc0[1], -(qc[q][0][1] * ks0[1]));
                float n2 = fmaf(qs[q][0][2], kc0[2], -(qc[q][0][2] * ks0[2]));
                float n3 = fmaf(qs[q][0][3], kc0[3], -(qc[q][0][3] * ks0[3]));
                float n4 = fmaf(qs[q][1][0], kc1[0], -(qc[q][1][0] * ks1[0]));
                float n5 = fmaf(qs[q][1][1], kc1[1], -(qc[q][1][1] * ks1[1]));
                float n6 = fmaf(qs[q][1][2], kc1[2], -(qc[q][1][2] * ks1[2]));
                float n7 = fmaf(qs[q][1][3], kc1[3], -(qc[q][1][3] * ks1[3]));
                float uh = ((u0 * u1) * (u2 * u3)) * ((u4 * u5) * (u6 * u7));
                float nh = ((n0 * n1) * (n2 * n3)) * ((n4 * n5) * (n6 * n7));
                // v_min3-fusable guard tree (abs folds as src modifier)
                float ma = fminf(fminf(fabsf(u0), fabsf(u1)), fabsf(u2));
                float mb = fminf(fminf(fabsf(u3), fabsf(u4)), fabsf(u5));
                float mc = fminf(fminf(fabsf(u6), fabsf(u7)), ma);
                float mn = fminf(mb, mc);
                if (__builtin_expect(mn < TGUARD, 0)) {
                    // lane-local guarded recompute of own half (rare)
                    float pu = 1.0f, pn = 1.0f;
#pragma unroll
                    for (int j = 0; j < 2; ++j) {
#pragma unroll
                        for (int e = 0; e < 4; ++e) {
                            float kpj = (j ? kp1 : kp0)[e];
                            float ksj = (j ? ks1 : ks0)[e];
                            float kcj = (j ? kc1 : kc0)[e];
                            float u = qp[q][j][e] - kpj;
                            float n = fmaf(qs[q][j][e], kcj, -(qc[q][j][e] * ksj));
                            if (fabsf(u) < TGUARD) {
                                float ru = R * u;
                                n = R * fmaf(-ru * ru, 0.16666667f, 1.0f);
                                u = 1.0f;
                            }
                            pu *= u; pn *= n;
                        }
                    }
                    if (fabsf(pu) < 1e-30f) pu = (pu < 0.0f) ? -1e-30f : 1e-30f;
                    uh = pu; nh = pn;
                }
                g[q] = nh * __builtin_amdgcn_rcpf(uh);
            }

            // pair exchange: dhalf0 stores q0 (needs partner's q0 half),
            // dhalf1 stores q1; one shfl each direction.
            float send = dhalf ? g[0] : g[1];
            float recv = __shfl_xor(send, 32, 64);
            float mine = dhalf ? g[1] : g[0];

            __builtin_nontemporal_store(fabsf(mine * recv),
                                        outRow + (size_t)(w * 2 + t) * 32);
        }

        if (w < 63) {
            // counted-vmcnt barrier: queue tail = [3 loads][2 stores] ->
            // vmcnt(2) proves next window's staging landed; stores fly on.
            __builtin_amdgcn_sched_barrier(0);
            asm volatile("s_waitcnt vmcnt(2)\n\ts_barrier");
            __builtin_amdgcn_sched_barrier(0);
        }
    }
}

extern "C" void kernel_launch(void* const* d_in, const int* in_sizes, int n_in,
                              void* d_out, int out_size, void* d_ws, size_t ws_size,
                              hipStream_t stream)
{
    const float* h    = (const float*)d_in[0];   // [1024,4,128]
    const float* mems = (const float*)d_in[1];   // [1024,4,128]
    const float* Wq   = (const float*)d_in[2];   // [128,128]
    const float* Wk   = (const float*)d_in[3];   // [128,128]
    const float* R    = (const float*)d_in[4];   // [8]
    float* out = (float*)d_out;                  // [1024,2048,4,8] fp32

    float* Rq3 = (float*)d_ws;                   // 1024*1536 floats (6 MB)
    float* Rk3 = Rq3 + (size_t)1024 * 1536;      // 2048*1536 floats (12 MB)

    fa_proj_kernel<<<dim3(384), 256, 0, stream>>>(h, mems, Wq, Wk, R, Rq3, Rk3);

    // 128 q-blocks x 16 k-chunks = 2048 blocks; bid&15 = chunk (XCD-clean)
    fa_fourier_main<<<dim3(2048), 256, 0, stream>>>(Rq3, Rk3, R, out);
}